// Round 2
// baseline (154104.028 us; speedup 1.0000x reference)
//
// Round 2: occupancy + k-split. 256 WG x 1024 threads (4 waves/SIMD).
// Phase A: L1@s (j x 2 kparts), L2@s-1, L3@s-2 (j x 4 kparts), LDS partial reduce.
// Phase B: attention@s (WG 0..63) + out-proj@s-3 (WG 64..94, 4 kparts/o).
// 2 grid syncs per superstep, 603 supersteps. All fp32.

#include <hip/hip_runtime.h>
#include <hip/hip_cooperative_groups.h>

namespace cg = cooperative_groups;

#define HB   400
#define KK   10
#define VV   77
#define OO   121
#define BB   64
#define TT   600
#define UU   64

#define NTHREADS (256 * 1024)
#define HBSTRIDE 25600   // H*B
#define WSTRIDE  4928    // V*B

struct Args {
  const float* __restrict__ x;
  const int*   __restrict__ text;
  const float* __restrict__ mask;
  const float* __restrict__ Wih1; const float* __restrict__ Whh1; const float* __restrict__ b1;
  const float* __restrict__ Wih2; const float* __restrict__ Whh2; const float* __restrict__ b2;
  const float* __restrict__ Wih3; const float* __restrict__ Whh3; const float* __restrict__ b3;
  const float* __restrict__ Wwin; const float* __restrict__ bwin;
  const float* __restrict__ Wout; const float* __restrict__ bout;
  float* __restrict__ out;
  float* __restrict__ ws;
};

__device__ __forceinline__ float sigm(float v) { return 1.0f / (1.0f + __expf(-v)); }

// 4-gate dot over one contiguous segment; state layout [k][64], weights row +
// gate offset goff (= 400*LD).
__device__ __forceinline__ void dotseg(const float* __restrict__ w, int goff,
    const float* __restrict__ st, int lane, int cnt, float4& a) {
  #pragma unroll 4
  for (int k = 0; k < cnt; ++k) {
    float v = st[(size_t)k * 64 + lane];
    a.x = fmaf(w[k], v, a.x);
    a.y = fmaf(w[goff + k], v, a.y);
    a.z = fmaf(w[2 * goff + k], v, a.z);
    a.w = fmaf(w[3 * goff + k], v, a.w);
  }
}

__device__ __forceinline__ void runseg(const float* w, int goff, const float* st,
    int len, int& pos, int k0, int k1, int lane, float4& a) {
  int s0 = k0 - pos, s1 = k1 - pos;
  if (s0 < 0) s0 = 0;
  if (s1 > len) s1 = len;
  if (s1 > s0) dotseg(w + s0, goff, st + (size_t)s0 * 64, lane, s1 - s0, a);
  pos += len;
}

// single-accumulator version (out projection)
__device__ __forceinline__ void dotseg1(const float* __restrict__ w,
    const float* __restrict__ st, int lane, int cnt, float& a) {
  #pragma unroll 8
  for (int k = 0; k < cnt; ++k) a = fmaf(w[k], st[(size_t)k * 64 + lane], a);
}

__device__ __forceinline__ void runseg1(const float* w, const float* st,
    int len, int& pos, int k0, int k1, int lane, float& a) {
  int s0 = k0 - pos, s1 = k1 - pos;
  if (s0 < 0) s0 = 0;
  if (s1 > len) s1 = len;
  if (s1 > s0) dotseg1(w + s0, st + (size_t)s0 * 64, lane, s1 - s0, a);
  pos += len;
}

__global__ __launch_bounds__(1024, 4) void hsnet_kernel(Args A) {
  cg::grid_group grid = cg::this_grid();
  const int lid  = threadIdx.x;
  const int wg   = blockIdx.x;
  const int lane = lid & 63;
  const int wv   = __builtin_amdgcn_readfirstlane(lid >> 6);   // 0..15
  const int tid  = wg * 1024 + lid;

  // Workspace layout (floats)
  float* h1r  = A.ws;                    // 4 * 25600
  float* h2r  = h1r + 4 * HBSTRIDE;
  float* h3r  = h2r + 4 * HBSTRIDE;
  float* c1   = h3r + 4 * HBSTRIDE;      // 25600 each
  float* c2   = c1 + HBSTRIDE;
  float* c3   = c2 + HBSTRIDE;
  float* wrng = c3 + HBSTRIDE;           // 4 * 4928
  float* kap  = wrng + 4 * WSTRIDE;      // 640
  float* xT   = kap + KK * BB;           // 600*3*64

  __shared__ float pA[16][4][64];        // 16 KB: phase-A partials / phase-B out partials
  __shared__ float sred[240];
  __shared__ float smix[30];
  __shared__ float skap[KK];
  __shared__ float sphi[UU];
  __shared__ int   stext[UU];
  float (*pO)[64] = (float(*)[64])&pA[0][0][0];

  // ---- prologue: zero state, transpose x to (T,3,B) ----
  for (int i = tid; i < 404352; i += NTHREADS) A.ws[i] = 0.0f;
  for (int i = tid; i < TT * 3 * BB; i += NTHREADS) {
    int b = i & 63; int tj = i >> 6; int t = tj / 3; int jj = tj - t * 3;
    xT[i] = A.x[(b * TT + t) * 3 + jj];
  }
  __threadfence();
  grid.sync();

  // phase-A wave mapping (static): gid -> (layer, j, kp)
  const int gid = __builtin_amdgcn_readfirstlane(wg * 16 + wv);
  int layer = 0, j = 0, kp = 0, ksz = 0, Ktot = 0;
  if (gid < 800)       { layer = 1; j = gid >> 1;          kp = gid & 1;          ksz = 240; Ktot = 480; }
  else if (gid < 2400) { layer = 2; j = (gid - 800) >> 2;  kp = (gid - 800) & 3;  ksz = 220; Ktot = 880; }
  else if (gid < 4000) { layer = 3; j = (gid - 2400) >> 2; kp = (gid - 2400) & 3; ksz = 220; Ktot = 880; }

  // finisher mapping (per WG, uniform)
  int layerWG = 0, ncell = 0, npart = 0, jbase = 0;
  if (wg < 50)       { layerWG = 1; ncell = 8; npart = 2; jbase = wg * 8; }
  else if (wg < 150) { layerWG = 2; ncell = 4; npart = 4; jbase = (wg - 50) * 4; }
  else if (wg < 250) { layerWG = 3; ncell = 4; npart = 4; jbase = (wg - 150) * 4; }

  for (int s = 0; s < TT + 3; ++s) {
    // ================= phase A: LSTM gate partials =================
    {
      bool act = false;
      float4 acc = {0.f, 0.f, 0.f, 0.f};
      int k0 = kp * ksz, k1 = kp * ksz + ksz;
      if (layer == 1 && s < TT) {
        act = true; int t = s;
        const float* w01 = A.Wih1 + j * 80;
        const float* w2  = A.Whh1 + j * 400;
        int pos = 0;
        runseg(w01,     32000,  xT + t * 192,                     3,   pos, k0, k1, lane, acc);
        runseg(w01 + 3, 32000,  wrng + ((t - 1) & 3) * WSTRIDE,   77,  pos, k0, k1, lane, acc);
        runseg(w2,      160000, h1r + ((t - 1) & 3) * HBSTRIDE,   400, pos, k0, k1, lane, acc);
      } else if (layer == 2 && s >= 1 && s <= TT) {
        act = true; int t = s - 1;
        const float* w01 = A.Wih2 + j * 480;
        const float* w2  = A.Whh2 + j * 400;
        int pos = 0;
        runseg(w01,       192000, xT + t * 192,                   3,   pos, k0, k1, lane, acc);
        runseg(w01 + 3,   192000, h1r + (t & 3) * HBSTRIDE,       400, pos, k0, k1, lane, acc);
        runseg(w01 + 403, 192000, wrng + (t & 3) * WSTRIDE,       77,  pos, k0, k1, lane, acc);
        runseg(w2,        160000, h2r + ((t - 1) & 3) * HBSTRIDE, 400, pos, k0, k1, lane, acc);
      } else if (layer == 3 && s >= 2 && s <= TT + 1) {
        act = true; int t = s - 2;
        const float* w01 = A.Wih3 + j * 480;
        const float* w2  = A.Whh3 + j * 400;
        int pos = 0;
        runseg(w01,       192000, xT + t * 192,                   3,   pos, k0, k1, lane, acc);
        runseg(w01 + 3,   192000, h2r + (t & 3) * HBSTRIDE,       400, pos, k0, k1, lane, acc);
        runseg(w01 + 403, 192000, wrng + (t & 3) * WSTRIDE,       77,  pos, k0, k1, lane, acc);
        runseg(w2,        160000, h3r + ((t - 1) & 3) * HBSTRIDE, 400, pos, k0, k1, lane, acc);
      }
      if (act) {
        pA[wv][0][lane] = acc.x; pA[wv][1][lane] = acc.y;
        pA[wv][2][lane] = acc.z; pA[wv][3][lane] = acc.w;
      }
      __syncthreads();
      // finisher: one wave per cell
      bool factive = (layerWG == 1 && s < TT) ||
                     (layerWG == 2 && s >= 1 && s <= TT) ||
                     (layerWG == 3 && s >= 2 && s <= TT + 1);
      if (factive && wv < ncell) {
        int t = (layerWG == 1) ? s : (layerWG == 2 ? s - 1 : s - 2);
        const float* bias = (layerWG == 1) ? A.b1 : (layerWG == 2 ? A.b2 : A.b3);
        float* cst  = (layerWG == 1) ? c1  : (layerWG == 2 ? c2  : c3);
        float* hrng = (layerWG == 1) ? h1r : (layerWG == 2 ? h2r : h3r);
        int jj = jbase + wv;
        float g0 = 0.f, g1 = 0.f, g2 = 0.f, g3 = 0.f;
        for (int p = 0; p < npart; ++p) {
          int pw = wv * npart + p;
          g0 += pA[pw][0][lane]; g1 += pA[pw][1][lane];
          g2 += pA[pw][2][lane]; g3 += pA[pw][3][lane];
        }
        g0 += bias[jj]; g1 += bias[400 + jj]; g2 += bias[800 + jj]; g3 += bias[1200 + jj];
        float ig = sigm(g0), fg = sigm(g1), gg = tanhf(g2), og = sigm(g3);
        float cn = fg * cst[jj * 64 + lane] + ig * gg;
        cst[jj * 64 + lane] = cn;
        hrng[(t & 3) * HBSTRIDE + jj * 64 + lane] = og * tanhf(cn);
      }
    }
    __threadfence();
    grid.sync();

    // ================= phase B: attention + out-proj =================
    if (wg < BB) {
      if (s < TT) {
        const int b = wg;
        const float* h1t = h1r + (s & 3) * HBSTRIDE;
        if (lid < 240) {
          int g = lid >> 3, part = lid & 7;
          const float* wr = A.Wwin + g * HB;
          float acc = 0.0f;
          int k0 = part * 50;
          #pragma unroll 5
          for (int k = k0; k < k0 + 50; ++k) acc += wr[k] * h1t[k * BB + b];
          sred[lid] = acc;
        }
        if (lid < UU) stext[lid] = A.text[b * UU + lid];
        __syncthreads();
        if (lid < 30) {
          float m = A.bwin[lid];
          #pragma unroll
          for (int p2 = 0; p2 < 8; ++p2) m += sred[lid * 8 + p2];
          smix[lid] = __expf(m);
        }
        __syncthreads();
        if (lid < KK) {
          float kn = kap[lid * BB + b] + smix[20 + lid];
          kap[lid * BB + b] = kn;
          skap[lid] = kn;
        }
        __syncthreads();
        if (lid < UU) {
          float u = (float)lid;
          float phi = 0.0f;
          #pragma unroll
          for (int k = 0; k < KK; ++k) {
            float d = skap[k] - u;
            phi += smix[k] * __expf(-smix[10 + k] * d * d);
          }
          phi *= A.mask[b * UU + lid];
          sphi[lid] = phi;
        }
        __syncthreads();
        if (lid < VV) {
          float acc = 0.0f;
          for (int u2 = 0; u2 < UU; ++u2)
            acc += (stext[u2] == lid) ? sphi[u2] : 0.0f;
          wrng[(s & 3) * WSTRIDE + lid * BB + b] = acc;
        }
      }
    } else if (wg < 95 && s >= 3) {
      const int t = s - 3;
      const int slot = t & 3;
      int q   = wv >> 2;           // local o index 0..3
      int kp2 = wv & 3;
      int o   = (wg - 64) * 4 + q;
      bool act = (o < OO);
      if (act) {
        const float* wr = A.Wout + o * 1200;
        float a = 0.f;
        int pos = 0, k0 = kp2 * 300, k1 = k0 + 300;
        runseg1(wr,       h1r + slot * HBSTRIDE, 400, pos, k0, k1, lane, a);
        runseg1(wr + 400, h2r + slot * HBSTRIDE, 400, pos, k0, k1, lane, a);
        runseg1(wr + 800, h3r + slot * HBSTRIDE, 400, pos, k0, k1, lane, a);
        pO[wv][lane] = a;
      }
      __syncthreads();
      if (act && kp2 == 0) {
        float r = pO[wv][lane] + pO[wv + 1][lane] + pO[wv + 2][lane] + pO[wv + 3][lane]
                + A.bout[o];
        A.out[((size_t)lane * TT + t) * OO + o] = r;
      }
    }
    __threadfence();
    grid.sync();
  }
}

extern "C" void kernel_launch(void* const* d_in, const int* in_sizes, int n_in,
                              void* d_out, int out_size, void* d_ws, size_t ws_size,
                              hipStream_t stream) {
  Args a;
  a.x    = (const float*)d_in[0];
  a.text = (const int*)  d_in[1];
  a.mask = (const float*)d_in[2];
  a.Wih1 = (const float*)d_in[3];  a.Whh1 = (const float*)d_in[4];  a.b1 = (const float*)d_in[5];
  a.Wih2 = (const float*)d_in[6];  a.Whh2 = (const float*)d_in[7];  a.b2 = (const float*)d_in[8];
  a.Wih3 = (const float*)d_in[9];  a.Whh3 = (const float*)d_in[10]; a.b3 = (const float*)d_in[11];
  a.Wwin = (const float*)d_in[12]; a.bwin = (const float*)d_in[13];
  a.Wout = (const float*)d_in[14]; a.bout = (const float*)d_in[15];
  a.out  = (float*)d_out;
  a.ws   = (float*)d_ws;
  void* kargs[] = { &a };
  hipLaunchCooperativeKernel((const void*)hsnet_kernel, dim3(256), dim3(1024),
                             kargs, 0, stream);
}

// Round 6
// 153810.730 us; speedup vs baseline: 1.0019x; 1.0019x over previous
//
// Round 6: all-wave release fence in treebar (restore r1/r2's proven pattern).
// r5 post-mortem: first call passed, a timed REPLAY failed -> rare race in the
// barrier's release path. r1/r2 (correct incl. replays) had __threadfence() in
// ALL threads before the arrival protocol; r4/r5 used a wave0-only release
// fence and were wrong (badly/rarely). Fix: __threadfence() in all waves
// BEFORE the first __syncthreads; keep r5's all-wave acquire fence after the
// final __syncthreads. Protocol atomics stay relaxed (ordering via in-wave
// fence->atomic and control dependencies). Everything else identical to r5.

#include <hip/hip_runtime.h>
#include <hip/hip_cooperative_groups.h>

namespace cg = cooperative_groups;

#define HB   400
#define KK   10
#define VV   77
#define OO   121
#define BB   64
#define TT   600
#define UU   64

#define NTHREADS (256 * 1024)
#define HBSTRIDE 25600   // H*B
#define WSTRIDE  4928    // V*B
#define BAR_OFF  519680  // float index of barrier region; xT ends at 519552

struct Args {
  const float* __restrict__ x;
  const int*   __restrict__ text;
  const float* __restrict__ mask;
  const float* __restrict__ Wih1; const float* __restrict__ Whh1; const float* __restrict__ b1;
  const float* __restrict__ Wih2; const float* __restrict__ Whh2; const float* __restrict__ b2;
  const float* __restrict__ Wih3; const float* __restrict__ Whh3; const float* __restrict__ b3;
  const float* __restrict__ Wwin; const float* __restrict__ bwin;
  const float* __restrict__ Wout; const float* __restrict__ bout;
  float* __restrict__ out;
  float* __restrict__ ws;
};

__device__ __forceinline__ float sigm(float v) { return 1.0f / (1.0f + __expf(-v)); }

// --- custom 2-level grid barrier -------------------------------------------
// bar layout (uints, 64-uint = 256B spacing):
//   bar[g*64]        g=0..15  group arrival counters (written only, never polled)
//   bar[1024]                 root arrival counter
//   bar[1088]                 root generation (polled by 16 group leaders)
//   bar[1152+g*64]   g=0..15  group generation (polled by <=15 members each)
// Monotonic counters: barrier instance bc expects counter to pass bc*16+15.
__device__ __forceinline__ void treebar(unsigned int* bar, int wg, int lid,
                                        unsigned int bc) {
  // ALL waves: full release (waitcnt + buffer_wbl2 + waitcnt). This is the
  // r1/r2-proven release pattern; a wave0-only wbl2 raced rarely (r4/r5).
  __threadfence();
  __syncthreads();
  if (lid == 0) {
    const int g = wg >> 4;
    unsigned int old = __hip_atomic_fetch_add(bar + g * 64, 1u,
                         __ATOMIC_RELAXED, __HIP_MEMORY_SCOPE_AGENT);
    if (old == bc * 16u + 15u) {                        // last WG of group
      unsigned int r = __hip_atomic_fetch_add(bar + 1024, 1u,
                         __ATOMIC_RELAXED, __HIP_MEMORY_SCOPE_AGENT);
      if (r == bc * 16u + 15u)                          // last group overall
        __hip_atomic_store(bar + 1088, bc + 1u,
                           __ATOMIC_RELAXED, __HIP_MEMORY_SCOPE_AGENT);
    }
    if ((wg & 15) == 0) {                               // group leader
      while (__hip_atomic_load(bar + 1088, __ATOMIC_RELAXED,
                               __HIP_MEMORY_SCOPE_AGENT) <= bc)
        __builtin_amdgcn_s_sleep(2);
      __hip_atomic_store(bar + 1152 + g * 64, bc + 1u,
                         __ATOMIC_RELAXED, __HIP_MEMORY_SCOPE_AGENT);
    } else {
      while (__hip_atomic_load(bar + 1152 + g * 64, __ATOMIC_RELAXED,
                               __HIP_MEMORY_SCOPE_AGENT) <= bc)
        __builtin_amdgcn_s_sleep(2);
    }
  }
  __syncthreads();
  // Every wave invalidates its own cache view before issuing next-phase loads.
  __builtin_amdgcn_fence(__ATOMIC_ACQUIRE, "agent");
}

// 4-gate dot over one contiguous segment; state layout [k][64].
__device__ __forceinline__ void dotseg(const float* __restrict__ w, int goff,
    const float* __restrict__ st, int lane, int cnt, float4& a) {
  #pragma unroll 4
  for (int k = 0; k < cnt; ++k) {
    float v = st[(size_t)k * 64 + lane];
    a.x = fmaf(w[k], v, a.x);
    a.y = fmaf(w[goff + k], v, a.y);
    a.z = fmaf(w[2 * goff + k], v, a.z);
    a.w = fmaf(w[3 * goff + k], v, a.w);
  }
}

__device__ __forceinline__ void runseg(const float* w, int goff, const float* st,
    int len, int& pos, int k0, int k1, int lane, float4& a) {
  int s0 = k0 - pos, s1 = k1 - pos;
  if (s0 < 0) s0 = 0;
  if (s1 > len) s1 = len;
  if (s1 > s0) dotseg(w + s0, goff, st + (size_t)s0 * 64, lane, s1 - s0, a);
  pos += len;
}

__device__ __forceinline__ void dotseg1(const float* __restrict__ w,
    const float* __restrict__ st, int lane, int cnt, float& a) {
  #pragma unroll 8
  for (int k = 0; k < cnt; ++k) a = fmaf(w[k], st[(size_t)k * 64 + lane], a);
}

__device__ __forceinline__ void runseg1(const float* w, const float* st,
    int len, int& pos, int k0, int k1, int lane, float& a) {
  int s0 = k0 - pos, s1 = k1 - pos;
  if (s0 < 0) s0 = 0;
  if (s1 > len) s1 = len;
  if (s1 > s0) dotseg1(w + s0, st + (size_t)s0 * 64, lane, s1 - s0, a);
  pos += len;
}

__global__ __launch_bounds__(1024, 4) void hsnet_kernel(Args A) {
  cg::grid_group grid = cg::this_grid();
  const int lid  = threadIdx.x;
  const int wg   = blockIdx.x;
  const int lane = lid & 63;
  const int wv   = __builtin_amdgcn_readfirstlane(lid >> 6);   // 0..15
  const int tid  = wg * 1024 + lid;

  // Workspace layout (floats)
  float* h1r  = A.ws;                    // 4 * 25600          [0      .. 102400)
  float* h2r  = h1r + 4 * HBSTRIDE;      //                    [102400 .. 204800)
  float* h3r  = h2r + 4 * HBSTRIDE;      //                    [204800 .. 307200)
  float* c1   = h3r + 4 * HBSTRIDE;      // 25600 each         [307200 .. 332800)
  float* c2   = c1 + HBSTRIDE;           //                    [332800 .. 358400)
  float* c3   = c2 + HBSTRIDE;           //                    [358400 .. 384000)
  float* wrng = c3 + HBSTRIDE;           // 4 * 4928           [384000 .. 403712)
  float* kap  = wrng + 4 * WSTRIDE;      // 640                [403712 .. 404352)
  float* xT   = kap + KK * BB;           // 115200             [404352 .. 519552)
  unsigned int* bar = (unsigned int*)(A.ws + BAR_OFF);  // 2176 uints at 519680

  __shared__ float pA[16][4][64];
  __shared__ float sred[240];
  __shared__ float smix[30];
  __shared__ float skap[KK];
  __shared__ float sphi[UU];
  __shared__ int   stext[UU];
  float (*pO)[64] = (float(*)[64])&pA[0][0][0];

  // ---- prologue: zero state + barrier counters, transpose x to (T,3,B) ----
  for (int i = tid; i < BAR_OFF + 2176; i += NTHREADS) A.ws[i] = 0.0f;
  for (int i = tid; i < TT * 3 * BB; i += NTHREADS) {
    int b = i & 63; int tj = i >> 6; int t = tj / 3; int jj = tj - t * 3;
    xT[i] = A.x[(b * TT + t) * 3 + jj];
  }
  __threadfence();
  grid.sync();   // single cg sync to order prologue (incl. barrier zeroing)

  // phase-A wave mapping (static): gid -> (layer, j, kp)
  const int gid = __builtin_amdgcn_readfirstlane(wg * 16 + wv);
  int layer = 0, j = 0, kp = 0, ksz = 0;
  if (gid < 800)       { layer = 1; j = gid >> 1;          kp = gid & 1;          ksz = 240; }
  else if (gid < 2400) { layer = 2; j = (gid - 800) >> 2;  kp = (gid - 800) & 3;  ksz = 220; }
  else if (gid < 4000) { layer = 3; j = (gid - 2400) >> 2; kp = (gid - 2400) & 3; ksz = 220; }

  // finisher mapping (per WG, uniform)
  int layerWG = 0, ncell = 0, npart = 0, jbase = 0;
  if (wg < 50)       { layerWG = 1; ncell = 8; npart = 2; jbase = wg * 8; }
  else if (wg < 150) { layerWG = 2; ncell = 4; npart = 4; jbase = (wg - 50) * 4; }
  else if (wg < 250) { layerWG = 3; ncell = 4; npart = 4; jbase = (wg - 150) * 4; }

  unsigned int bc = 0;

  for (int s = 0; s < TT + 3; ++s) {
    // ================= phase A: LSTM gate partials =================
    {
      bool act = false;
      float4 acc = {0.f, 0.f, 0.f, 0.f};
      int k0 = kp * ksz, k1 = kp * ksz + ksz;
      if (layer == 1 && s < TT) {
        act = true; int t = s;
        const float* w01 = A.Wih1 + j * 80;
        const float* w2  = A.Whh1 + j * 400;
        int pos = 0;
        runseg(w01,     32000,  xT + t * 192,                     3,   pos, k0, k1, lane, acc);
        runseg(w01 + 3, 32000,  wrng + ((t - 1) & 3) * WSTRIDE,   77,  pos, k0, k1, lane, acc);
        runseg(w2,      160000, h1r + ((t - 1) & 3) * HBSTRIDE,   400, pos, k0, k1, lane, acc);
      } else if (layer == 2 && s >= 1 && s <= TT) {
        act = true; int t = s - 1;
        const float* w01 = A.Wih2 + j * 480;
        const float* w2  = A.Whh2 + j * 400;
        int pos = 0;
        runseg(w01,       192000, xT + t * 192,                   3,   pos, k0, k1, lane, acc);
        runseg(w01 + 3,   192000, h1r + (t & 3) * HBSTRIDE,       400, pos, k0, k1, lane, acc);
        runseg(w01 + 403, 192000, wrng + (t & 3) * WSTRIDE,       77,  pos, k0, k1, lane, acc);
        runseg(w2,        160000, h2r + ((t - 1) & 3) * HBSTRIDE, 400, pos, k0, k1, lane, acc);
      } else if (layer == 3 && s >= 2 && s <= TT + 1) {
        act = true; int t = s - 2;
        const float* w01 = A.Wih3 + j * 480;
        const float* w2  = A.Whh3 + j * 400;
        int pos = 0;
        runseg(w01,       192000, xT + t * 192,                   3,   pos, k0, k1, lane, acc);
        runseg(w01 + 3,   192000, h2r + (t & 3) * HBSTRIDE,       400, pos, k0, k1, lane, acc);
        runseg(w01 + 403, 192000, wrng + (t & 3) * WSTRIDE,       77,  pos, k0, k1, lane, acc);
        runseg(w2,        160000, h3r + ((t - 1) & 3) * HBSTRIDE, 400, pos, k0, k1, lane, acc);
      }
      if (act) {
        pA[wv][0][lane] = acc.x; pA[wv][1][lane] = acc.y;
        pA[wv][2][lane] = acc.z; pA[wv][3][lane] = acc.w;
      }
      __syncthreads();
      bool factive = (layerWG == 1 && s < TT) ||
                     (layerWG == 2 && s >= 1 && s <= TT) ||
                     (layerWG == 3 && s >= 2 && s <= TT + 1);
      if (factive && wv < ncell) {
        int t = (layerWG == 1) ? s : (layerWG == 2 ? s - 1 : s - 2);
        const float* bias = (layerWG == 1) ? A.b1 : (layerWG == 2 ? A.b2 : A.b3);
        float* cst  = (layerWG == 1) ? c1  : (layerWG == 2 ? c2  : c3);
        float* hrng = (layerWG == 1) ? h1r : (layerWG == 2 ? h2r : h3r);
        int jj = jbase + wv;
        float g0 = 0.f, g1 = 0.f, g2 = 0.f, g3 = 0.f;
        for (int p = 0; p < npart; ++p) {
          int pw = wv * npart + p;
          g0 += pA[pw][0][lane]; g1 += pA[pw][1][lane];
          g2 += pA[pw][2][lane]; g3 += pA[pw][3][lane];
        }
        g0 += bias[jj]; g1 += bias[400 + jj]; g2 += bias[800 + jj]; g3 += bias[1200 + jj];
        float ig = sigm(g0), fg = sigm(g1), gg = tanhf(g2), og = sigm(g3);
        float cn = fg * cst[jj * 64 + lane] + ig * gg;
        cst[jj * 64 + lane] = cn;
        hrng[(t & 3) * HBSTRIDE + jj * 64 + lane] = og * tanhf(cn);
      }
    }
    treebar(bar, wg, lid, bc); bc++;

    // ================= phase B: attention + out-proj =================
    if (wg < BB) {
      if (s < TT) {
        const int b = wg;
        const float* h1t = h1r + (s & 3) * HBSTRIDE;
        if (lid < 240) {
          int g = lid >> 3, part = lid & 7;
          const float* wr = A.Wwin + g * HB;
          float acc = 0.0f;
          int k0 = part * 50;
          #pragma unroll 5
          for (int k = k0; k < k0 + 50; ++k) acc += wr[k] * h1t[k * BB + b];
          sred[lid] = acc;
        }
        if (lid < UU) stext[lid] = A.text[b * UU + lid];
        __syncthreads();
        if (lid < 30) {
          float m = A.bwin[lid];
          #pragma unroll
          for (int p2 = 0; p2 < 8; ++p2) m += sred[lid * 8 + p2];
          smix[lid] = __expf(m);
        }
        __syncthreads();
        if (lid < KK) {
          float kn = kap[lid * BB + b] + smix[20 + lid];
          kap[lid * BB + b] = kn;
          skap[lid] = kn;
        }
        __syncthreads();
        if (lid < UU) {
          float u = (float)lid;
          float phi = 0.0f;
          #pragma unroll
          for (int k = 0; k < KK; ++k) {
            float d = skap[k] - u;
            phi += smix[k] * __expf(-smix[10 + k] * d * d);
          }
          phi *= A.mask[b * UU + lid];
          sphi[lid] = phi;
        }
        __syncthreads();
        if (lid < VV) {
          float acc = 0.0f;
          for (int u2 = 0; u2 < UU; ++u2)
            acc += (stext[u2] == lid) ? sphi[u2] : 0.0f;
          wrng[(s & 3) * WSTRIDE + lid * BB + b] = acc;
        }
      }
    } else if (wg < 95 && s >= 3) {
      const int t = s - 3;
      const int slot = t & 3;
      int q   = wv >> 2;
      int kp2 = wv & 3;
      int o   = (wg - 64) * 4 + q;
      bool act = (o < OO);
      if (act) {
        const float* wr = A.Wout + o * 1200;
        float a = 0.f;
        int pos = 0, k0 = kp2 * 300, k1 = k0 + 300;
        runseg1(wr,       h1r + slot * HBSTRIDE, 400, pos, k0, k1, lane, a);
        runseg1(wr + 400, h2r + slot * HBSTRIDE, 400, pos, k0, k1, lane, a);
        runseg1(wr + 800, h3r + slot * HBSTRIDE, 400, pos, k0, k1, lane, a);
        pO[wv][lane] = a;
      }
      __syncthreads();
      if (act && kp2 == 0) {
        float r = pO[wv][lane] + pO[wv + 1][lane] + pO[wv + 2][lane] + pO[wv + 3][lane]
                + A.bout[o];
        A.out[((size_t)lane * TT + t) * OO + o] = r;
      }
    }
    treebar(bar, wg, lid, bc); bc++;
  }
}

extern "C" void kernel_launch(void* const* d_in, const int* in_sizes, int n_in,
                              void* d_out, int out_size, void* d_ws, size_t ws_size,
                              hipStream_t stream) {
  Args a;
  a.x    = (const float*)d_in[0];
  a.text = (const int*)  d_in[1];
  a.mask = (const float*)d_in[2];
  a.Wih1 = (const float*)d_in[3];  a.Whh1 = (const float*)d_in[4];  a.b1 = (const float*)d_in[5];
  a.Wih2 = (const float*)d_in[6];  a.Whh2 = (const float*)d_in[7];  a.b2 = (const float*)d_in[8];
  a.Wih3 = (const float*)d_in[9];  a.Whh3 = (const float*)d_in[10]; a.b3 = (const float*)d_in[11];
  a.Wwin = (const float*)d_in[12]; a.bwin = (const float*)d_in[13];
  a.Wout = (const float*)d_in[14]; a.bout = (const float*)d_in[15];
  a.out  = (float*)d_out;
  a.ws   = (float*)d_ws;
  void* kargs[] = { &a };
  hipLaunchCooperativeKernel((const void*)hsnet_kernel, dim3(256), dim3(1024),
                             kargs, 0, stream);
}

// Round 8
// 74984.900 us; speedup vs baseline: 2.0551x; 2.0512x over previous
//
// Round 8: architectural rewrite — batch-parallel fully-fused private WGs.
// r2..r7 showed: correct grid-wide sync costs ~100+us/barrier on 8-XCD MI355X
// (cg == tree == 154ms; all cheaper-fence variants raced). Fix: exploit batch
// independence. 64 WGs x 1024 thr; WG b runs the ENTIRE 600-step recurrence
// for batch item b (L1 + attention + L2 + L3 + out-proj) with state in LDS and
// only __syncthreads() inside. Zero cross-WG communication after one prologue
// grid.sync (weights converted once to bf16-packed k-major layout in ws,
// ~7.5MB). Compute fp32 (bf16 unpack via shift/mask). No fences in the loop.

#include <hip/hip_runtime.h>
#include <hip/hip_cooperative_groups.h>

namespace cg = cooperative_groups;

#define HH 400
#define NK 10
#define VV 77
#define NO 121
#define TT 600
#define UU 64

#define NWG 64
#define NTH 1024

// packed bf16-pair weight regions in ws (u32 units)
#define KP1   240                    // K=480 pairs (L1: x3,w77,h1 400)
#define KP23  440                    // K=880 pairs (L2/3: x3,hprev400,w77,h 400)
#define KPO   600                    // K=1200 pairs (out: h1,h2,h3)
#define O_L1  0
#define O_L2  (KP1 * 1600)           // 384000
#define O_L3  (O_L2 + KP23 * 1600)   // 1088000
#define O_OUT (O_L3 + KP23 * 1600)   // 1792000
#define N_TOT (O_OUT + KPO * 128)    // 1868800 u32 = 7.48 MB  (ws must be >= this)

struct Args {
  const float* __restrict__ x;
  const int*   __restrict__ text;
  const float* __restrict__ mask;
  const float* __restrict__ Wih1; const float* __restrict__ Whh1; const float* __restrict__ b1;
  const float* __restrict__ Wih2; const float* __restrict__ Whh2; const float* __restrict__ b2;
  const float* __restrict__ Wih3; const float* __restrict__ Whh3; const float* __restrict__ b3;
  const float* __restrict__ Wwin; const float* __restrict__ bwin;
  const float* __restrict__ Wout; const float* __restrict__ bout;
  float* __restrict__ out;
  float* __restrict__ ws;
};

__device__ __forceinline__ float sigm(float v) { return 1.0f / (1.0f + __expf(-v)); }

// f32 -> bf16 (round-to-nearest-even), returned in low 16 bits
__device__ __forceinline__ unsigned int bfr(float f) {
  unsigned int u = __builtin_bit_cast(unsigned int, f);
  return (u + 0x7fffu + ((u >> 16) & 1u)) >> 16;
}
__device__ __forceinline__ float blo(unsigned int w) {
  return __builtin_bit_cast(float, w << 16);
}
__device__ __forceinline__ float bhi(unsigned int w) {
  return __builtin_bit_cast(float, w & 0xffff0000u);
}

// Gate matvec: 1600 rows over K=2*KP inputs. Thread lid owns row lid; threads
// lid<576 also own row 1024+lid. Weights W[kp*1600 + r] (u32 = bf16 k-pair,
// lane-consecutive rows => coalesced). Inputs sv2[kp] (LDS, broadcast).
template<int KP>
__device__ __forceinline__ void gates(const unsigned int* __restrict__ W,
                                      const float* __restrict__ bias,
                                      const float2* __restrict__ sv2,
                                      float* __restrict__ sgate, int lid)
{
  const unsigned int* w0 = W + lid;
  if (lid < 576) {
    float a0 = bias[lid];
    float a1 = bias[1024 + lid];
    const unsigned int* w1 = W + 1024 + lid;
    #pragma unroll 4
    for (int kp = 0; kp < KP; ++kp) {
      float2 v = sv2[kp];
      unsigned int p0 = w0[kp * 1600];
      unsigned int p1 = w1[kp * 1600];
      a0 = fmaf(blo(p0), v.x, a0); a0 = fmaf(bhi(p0), v.y, a0);
      a1 = fmaf(blo(p1), v.x, a1); a1 = fmaf(bhi(p1), v.y, a1);
    }
    sgate[lid] = a0; sgate[1024 + lid] = a1;
  } else {
    float a0 = bias[lid];
    #pragma unroll 4
    for (int kp = 0; kp < KP; ++kp) {
      float2 v = sv2[kp];
      unsigned int p0 = w0[kp * 1600];
      a0 = fmaf(blo(p0), v.x, a0); a0 = fmaf(bhi(p0), v.y, a0);
    }
    sgate[lid] = a0;
  }
}

__global__ __launch_bounds__(1024) void hsnet_kernel(Args A) {
  cg::grid_group grid = cg::this_grid();
  const int lid = threadIdx.x;
  const int b   = blockIdx.x;
  unsigned int* __restrict__ wsu = (unsigned int*)A.ws;

  // ================== prologue: weight conversion (one-time) ==================
  for (int i = b * NTH + lid; i < N_TOT; i += NWG * NTH) {
    float f0, f1;
    if (i < O_L2) {                       // L1: Wih1 (LD 80) then Whh1
      int kp = i / 1600, r = i - kp * 1600, k0 = 2 * kp;
      if (k0 < 80) { f0 = A.Wih1[r * 80 + k0];        f1 = A.Wih1[r * 80 + k0 + 1]; }
      else         { f0 = A.Whh1[r * 400 + k0 - 80];  f1 = A.Whh1[r * 400 + k0 - 79]; }
    } else if (i < O_L3) {                // L2: Wih2 (LD 480) then Whh2
      int j = i - O_L2;
      int kp = j / 1600, r = j - kp * 1600, k0 = 2 * kp;
      if (k0 < 480) { f0 = A.Wih2[r * 480 + k0];        f1 = A.Wih2[r * 480 + k0 + 1]; }
      else          { f0 = A.Whh2[r * 400 + k0 - 480];  f1 = A.Whh2[r * 400 + k0 - 479]; }
    } else if (i < O_OUT) {               // L3
      int j = i - O_L3;
      int kp = j / 1600, r = j - kp * 1600, k0 = 2 * kp;
      if (k0 < 480) { f0 = A.Wih3[r * 480 + k0];        f1 = A.Wih3[r * 480 + k0 + 1]; }
      else          { f0 = A.Whh3[r * 400 + k0 - 480];  f1 = A.Whh3[r * 400 + k0 - 479]; }
    } else {                              // Out: Wout (121x1200), rows padded to 128
      int j = i - O_OUT;
      int kp = j >> 7, o = j & 127, k0 = 2 * kp;
      f0 = (o < NO) ? A.Wout[o * 1200 + k0]     : 0.0f;
      f1 = (o < NO) ? A.Wout[o * 1200 + k0 + 1] : 0.0f;
    }
    wsu[i] = bfr(f0) | (bfr(f1) << 16);
  }
  grid.sync();   // sole cross-WG event; weights read-only afterwards

  const unsigned int* __restrict__ WL1 = wsu + O_L1;
  const unsigned int* __restrict__ WL2 = wsu + O_L2;
  const unsigned int* __restrict__ WL3 = wsu + O_L3;
  const unsigned int* __restrict__ WO  = wsu + O_OUT;

  // ================== per-WG private state (LDS) ==================
  __shared__ float2 sv2[KPO];            // layer input vector (pairs); f32 alias
  __shared__ float  sgate[1600];
  __shared__ float  sh1[HH], sh2[HH], sh3[HH];
  __shared__ float  sc1[HH], sc2[HH], sc3[HH];
  __shared__ float  sw[VV];
  __shared__ float  skap[NK];
  __shared__ float  sred[240], smix[30], sphi[UU], smask[UU];
  __shared__ int    stext[UU];
  __shared__ float  pO2[8][128];
  float* sval = (float*)sv2;

  if (lid < HH) { sh1[lid] = 0.f; sh2[lid] = 0.f; sh3[lid] = 0.f;
                  sc1[lid] = 0.f; sc2[lid] = 0.f; sc3[lid] = 0.f; }
  if (lid < VV) sw[lid] = 0.f;
  if (lid < NK) skap[lid] = 0.f;
  if (lid < UU) { stext[lid] = A.text[b * UU + lid]; smask[lid] = A.mask[b * UU + lid]; }
  __syncthreads();

  // ================== time loop: fully in-WG ==================
  for (int t = 0; t < TT; ++t) {
    const float* xt = A.x + ((size_t)b * TT + t) * 3;

    // ---- L1: val = [x(3), w(77), h1(400)] ----
    if (lid < 480)
      sval[lid] = (lid < 3) ? xt[lid] : (lid < 80) ? sw[lid - 3] : sh1[lid - 80];
    __syncthreads();
    gates<KP1>(WL1, A.b1, sv2, sgate, lid);
    __syncthreads();
    if (lid < HH) {
      float ig = sigm(sgate[lid]),       fg = sigm(sgate[400 + lid]);
      float gg = tanhf(sgate[800 + lid]), og = sigm(sgate[1200 + lid]);
      float cn = fg * sc1[lid] + ig * gg;
      sc1[lid] = cn; sh1[lid] = og * tanhf(cn);
    }
    __syncthreads();

    // ---- attention window (uses new h1) ----
    if (lid < 240) {
      int g = lid >> 3, part = lid & 7, k0 = part * 50;
      const float* wr = A.Wwin + g * HH;
      float acc = 0.f;
      #pragma unroll 5
      for (int k = k0; k < k0 + 50; ++k) acc += wr[k] * sh1[k];
      sred[lid] = acc;
    }
    __syncthreads();
    if (lid < 30) {
      float m = A.bwin[lid];
      #pragma unroll
      for (int p = 0; p < 8; ++p) m += sred[lid * 8 + p];
      smix[lid] = __expf(m);
    }
    __syncthreads();
    if (lid < NK) skap[lid] += smix[20 + lid];
    __syncthreads();
    if (lid < UU) {
      float u = (float)lid, phi = 0.f;
      #pragma unroll
      for (int k = 0; k < NK; ++k) {
        float d = skap[k] - u;
        phi += smix[k] * __expf(-smix[10 + k] * d * d);
      }
      sphi[lid] = phi * smask[lid];
    }
    __syncthreads();
    if (lid < VV) {
      float acc = 0.f;
      for (int u2 = 0; u2 < UU; ++u2)
        acc += (stext[u2] == lid) ? sphi[u2] : 0.f;
      sw[lid] = acc;
    }
    __syncthreads();

    // ---- L2: val = [x(3), h1(400), w(77), h2(400)] ----
    if (lid < 880)
      sval[lid] = (lid < 3) ? xt[lid] : (lid < 403) ? sh1[lid - 3]
                : (lid < 480) ? sw[lid - 403] : sh2[lid - 480];
    __syncthreads();
    gates<KP23>(WL2, A.b2, sv2, sgate, lid);
    __syncthreads();
    if (lid < HH) {
      float ig = sigm(sgate[lid]),       fg = sigm(sgate[400 + lid]);
      float gg = tanhf(sgate[800 + lid]), og = sigm(sgate[1200 + lid]);
      float cn = fg * sc2[lid] + ig * gg;
      sc2[lid] = cn; sh2[lid] = og * tanhf(cn);
    }
    __syncthreads();

    // ---- L3: val = [x(3), h2(400), w(77), h3(400)] ----
    if (lid < 880)
      sval[lid] = (lid < 3) ? xt[lid] : (lid < 403) ? sh2[lid - 3]
                : (lid < 480) ? sw[lid - 403] : sh3[lid - 480];
    __syncthreads();
    gates<KP23>(WL3, A.b3, sv2, sgate, lid);
    __syncthreads();
    if (lid < HH) {
      float ig = sigm(sgate[lid]),       fg = sigm(sgate[400 + lid]);
      float gg = tanhf(sgate[800 + lid]), og = sigm(sgate[1200 + lid]);
      float cn = fg * sc3[lid] + ig * gg;
      sc3[lid] = cn; sh3[lid] = og * tanhf(cn);
    }
    __syncthreads();

    // ---- out-proj: val = [h1|h2|h3] (1200) ----
    sval[lid] = (lid < 400) ? sh1[lid] : (lid < 800) ? sh2[lid - 400] : sh3[lid - 800];
    if (lid < 176) sval[1024 + lid] = sh3[224 + lid];
    __syncthreads();
    {
      int o = lid & 127, kpart = lid >> 7;
      const unsigned int* wo = WO + o;
      float a = 0.f;
      #pragma unroll 5
      for (int kp = kpart * 75; kp < kpart * 75 + 75; ++kp) {
        float2 v = sv2[kp];
        unsigned int p = wo[kp * 128];
        a = fmaf(blo(p), v.x, a); a = fmaf(bhi(p), v.y, a);
      }
      pO2[kpart][o] = a;
    }
    __syncthreads();
    if (lid < NO) {
      float r = A.bout[lid];
      #pragma unroll
      for (int q = 0; q < 8; ++q) r += pO2[q][lid];
      A.out[((size_t)b * TT + t) * NO + lid] = r;
    }
    __syncthreads();
  }
}

extern "C" void kernel_launch(void* const* d_in, const int* in_sizes, int n_in,
                              void* d_out, int out_size, void* d_ws, size_t ws_size,
                              hipStream_t stream) {
  Args a;
  a.x    = (const float*)d_in[0];
  a.text = (const int*)  d_in[1];
  a.mask = (const float*)d_in[2];
  a.Wih1 = (const float*)d_in[3];  a.Whh1 = (const float*)d_in[4];  a.b1 = (const float*)d_in[5];
  a.Wih2 = (const float*)d_in[6];  a.Whh2 = (const float*)d_in[7];  a.b2 = (const float*)d_in[8];
  a.Wih3 = (const float*)d_in[9];  a.Whh3 = (const float*)d_in[10]; a.b3 = (const float*)d_in[11];
  a.Wwin = (const float*)d_in[12]; a.bwin = (const float*)d_in[13];
  a.Wout = (const float*)d_in[14]; a.bout = (const float*)d_in[15];
  a.out  = (float*)d_out;
  a.ws   = (float*)d_ws;
  void* kargs[] = { &a };
  hipLaunchCooperativeKernel((const void*)hsnet_kernel, dim3(NWG), dim3(NTH),
                             kargs, 0, stream);
}

// Round 9
// 47819.687 us; speedup vs baseline: 3.2226x; 1.5681x over previous
//
// Round 9: r8 structure + f16 packed weights, v_dot2_f32_f16, dwordx4 loads.
// r8 PMC: active CUs ~56% VALU-busy, ~29K VMEM insts/step/CU -> inst-issue
// bound, not BW (252 GB/s). fdot2 halves VALU (2 MAC/inst, f32 accum);
// uint4 weight groups (4 half2 pairs/row) quarter VMEM insts.
// f32 kept for: cell c, gate preacts, attention mix/kappa/phi, output.
// f16 for: weights, matvec inputs (h,w,x). bf16 weights passed at 0.0156;
// f16 is strictly more precise. Structure/syncs identical to r8.

#include <hip/hip_runtime.h>
#include <hip/hip_cooperative_groups.h>

namespace cg = cooperative_groups;

#define HH 400
#define NK 10
#define VV 77
#define NO 121
#define TT 600
#define UU 64

#define NWG 64
#define NTH 1024

#define NG1  60     // L1: K=480 -> 60 groups of 8
#define NG23 110    // L2/L3: K=880 -> 110 groups
#define KPO  600    // out: K=1200 -> 600 half2 pairs

// u32 offsets in ws
#define O_L1  0
#define O_L2  384000              // 60*1600*4
#define O_L3  1088000             // + 110*1600*4
#define O_OUT 1792000             // + 110*1600*4
#define N_TOT 1868800             // + 600*128  = 7.48 MB

typedef _Float16 h2 __attribute__((ext_vector_type(2)));

struct Args {
  const float* __restrict__ x;
  const int*   __restrict__ text;
  const float* __restrict__ mask;
  const float* __restrict__ Wih1; const float* __restrict__ Whh1; const float* __restrict__ b1;
  const float* __restrict__ Wih2; const float* __restrict__ Whh2; const float* __restrict__ b2;
  const float* __restrict__ Wih3; const float* __restrict__ Whh3; const float* __restrict__ b3;
  const float* __restrict__ Wwin; const float* __restrict__ bwin;
  const float* __restrict__ Wout; const float* __restrict__ bout;
  float* __restrict__ out;
  float* __restrict__ ws;
};

__device__ __forceinline__ float sigm(float v) { return 1.0f / (1.0f + __expf(-v)); }

#if defined(__has_builtin)
#if __has_builtin(__builtin_amdgcn_fdot2)
#define FDOT2(a,b,c) __builtin_amdgcn_fdot2((a),(b),(c),false)
#endif
#endif
#ifndef FDOT2
#define FDOT2(a,b,c) fmaf((float)(a).x,(float)(b).x, fmaf((float)(a).y,(float)(b).y,(c)))
#endif

__device__ __forceinline__ h2 toh2(unsigned int u) { return __builtin_bit_cast(h2, u); }

__device__ __forceinline__ float dot4(uint4 p, uint4 v, float a) {
  a = FDOT2(toh2(p.x), toh2(v.x), a);
  a = FDOT2(toh2(p.y), toh2(v.y), a);
  a = FDOT2(toh2(p.z), toh2(v.z), a);
  a = FDOT2(toh2(p.w), toh2(v.w), a);
  return a;
}

__device__ __forceinline__ unsigned int packh2(float f0, float f1) {
  unsigned short lo = __builtin_bit_cast(unsigned short, (_Float16)f0);
  unsigned short hi = __builtin_bit_cast(unsigned short, (_Float16)f1);
  return (unsigned int)lo | ((unsigned int)hi << 16);
}

// Gate matvec: 1600 rows x K=8*NG. Row r of group g at W4[g*1600 + r] (uint4 =
// 4 half2 k-pairs). Threads 0..575 own rows {lid, 1024+lid}; 576..1023 own lid.
template<int NG>
__device__ __forceinline__ void gatesH(const unsigned int* __restrict__ Wu,
    const float* __restrict__ bias, const _Float16* __restrict__ svh,
    float* __restrict__ sgate, int lid)
{
  const uint4* W4 = (const uint4*)Wu;
  const uint4* vp = (const uint4*)svh;
  if (lid < 576) {
    float a0 = bias[lid], a1 = bias[1024 + lid];
    const uint4* p0 = W4 + lid;
    const uint4* p1 = W4 + 1024 + lid;
    #pragma unroll 2
    for (int g = 0; g < NG; ++g) {
      uint4 vv = vp[g];
      a0 = dot4(p0[g * 1600], vv, a0);
      a1 = dot4(p1[g * 1600], vv, a1);
    }
    sgate[lid] = a0; sgate[1024 + lid] = a1;
  } else {
    float a0 = bias[lid];
    const uint4* p0 = W4 + lid;
    #pragma unroll 2
    for (int g = 0; g < NG; ++g)
      a0 = dot4(p0[g * 1600], vp[g], a0);
    sgate[lid] = a0;
  }
}

__global__ __launch_bounds__(1024) void hsnet_kernel(Args A) {
  cg::grid_group grid = cg::this_grid();
  const int lid = threadIdx.x;
  const int b   = blockIdx.x;
  unsigned int* __restrict__ wsu = (unsigned int*)A.ws;

  // ============ prologue: one-time weight conversion to f16 groups ============
  // Gate layers: u32 index u -> g=u/6400, r=(u%6400)/4, j=u&3, k0=8g+2j.
  for (int i = b * NTH + lid; i < N_TOT; i += NWG * NTH) {
    float f0, f1;
    if (i < O_L2) {
      int u = i, g = u / 6400, rem = u - g * 6400, r = rem >> 2, jj = rem & 3;
      int k0 = 8 * g + 2 * jj;
      if (k0 < 80) { f0 = A.Wih1[r * 80 + k0];       f1 = A.Wih1[r * 80 + k0 + 1]; }
      else         { f0 = A.Whh1[r * 400 + k0 - 80]; f1 = A.Whh1[r * 400 + k0 - 79]; }
    } else if (i < O_L3) {
      int u = i - O_L2, g = u / 6400, rem = u - g * 6400, r = rem >> 2, jj = rem & 3;
      int k0 = 8 * g + 2 * jj;
      if (k0 < 480) { f0 = A.Wih2[r * 480 + k0];        f1 = A.Wih2[r * 480 + k0 + 1]; }
      else          { f0 = A.Whh2[r * 400 + k0 - 480];  f1 = A.Whh2[r * 400 + k0 - 479]; }
    } else if (i < O_OUT) {
      int u = i - O_L3, g = u / 6400, rem = u - g * 6400, r = rem >> 2, jj = rem & 3;
      int k0 = 8 * g + 2 * jj;
      if (k0 < 480) { f0 = A.Wih3[r * 480 + k0];        f1 = A.Wih3[r * 480 + k0 + 1]; }
      else          { f0 = A.Whh3[r * 400 + k0 - 480];  f1 = A.Whh3[r * 400 + k0 - 479]; }
    } else {                              // out: [kp*128 + o], rows padded to 128
      int u = i - O_OUT, kp = u >> 7, o = u & 127, k0 = 2 * kp;
      f0 = (o < NO) ? A.Wout[o * 1200 + k0]     : 0.0f;
      f1 = (o < NO) ? A.Wout[o * 1200 + k0 + 1] : 0.0f;
    }
    wsu[i] = packh2(f0, f1);
  }
  grid.sync();   // sole cross-WG event; weights read-only afterwards

  const unsigned int* __restrict__ WL1 = wsu + O_L1;
  const unsigned int* __restrict__ WL2 = wsu + O_L2;
  const unsigned int* __restrict__ WL3 = wsu + O_L3;
  const unsigned int* __restrict__ WO  = wsu + O_OUT;

  // ============ per-WG private state (LDS) ============
  __shared__ alignas(16) _Float16 svh[1216];   // matvec input vector (f16)
  __shared__ float    sgate[1600];
  __shared__ _Float16 shh[3][HH];              // h1,h2,h3 (f16)
  __shared__ float    sc[3][HH];               // cells (f32)
  __shared__ _Float16 swv[VV];                 // soft window (f16)
  __shared__ float    skap[NK];                // kappa (f32!)
  __shared__ float    sred[240], smix[30], sphi[UU], smask[UU];
  __shared__ int      stext[UU];
  __shared__ float    pO2[8][128];

  if (lid < HH) {
    shh[0][lid] = (_Float16)0.f; shh[1][lid] = (_Float16)0.f; shh[2][lid] = (_Float16)0.f;
    sc[0][lid] = 0.f; sc[1][lid] = 0.f; sc[2][lid] = 0.f;
  }
  if (lid < VV) swv[lid] = (_Float16)0.f;
  if (lid < NK) skap[lid] = 0.f;
  if (lid < UU) { stext[lid] = A.text[b * UU + lid]; smask[lid] = A.mask[b * UU + lid]; }
  __syncthreads();

  // ============ time loop, fully in-WG ============
  for (int t = 0; t < TT; ++t) {
    const float* xt = A.x + ((size_t)b * TT + t) * 3;

    // ---- L1 input: [x(3), w(77), h1(400)] ----
    if (lid < 480)
      svh[lid] = (lid < 3) ? (_Float16)xt[lid]
               : (lid < 80) ? swv[lid - 3] : shh[0][lid - 80];
    __syncthreads();
    gatesH<NG1>(WL1, A.b1, svh, sgate, lid);
    __syncthreads();
    if (lid < HH) {
      float ig = sigm(sgate[lid]),        fg = sigm(sgate[400 + lid]);
      float gg = tanhf(sgate[800 + lid]), og = sigm(sgate[1200 + lid]);
      float cn = fg * sc[0][lid] + ig * gg;
      sc[0][lid] = cn; shh[0][lid] = (_Float16)(og * tanhf(cn));
    }
    __syncthreads();

    // ---- attention window (new h1) ----
    if (lid < 240) {
      int g = lid >> 3, part = lid & 7, k0 = part * 50;
      const float* wr = A.Wwin + g * HH;
      float acc = 0.f;
      #pragma unroll 5
      for (int k = k0; k < k0 + 50; ++k) acc += wr[k] * (float)shh[0][k];
      sred[lid] = acc;
    }
    __syncthreads();
    if (lid < 30) {
      float m = A.bwin[lid];
      #pragma unroll
      for (int p = 0; p < 8; ++p) m += sred[lid * 8 + p];
      smix[lid] = __expf(m);
    }
    __syncthreads();
    if (lid < NK) skap[lid] += smix[20 + lid];
    __syncthreads();
    if (lid < UU) {
      float u = (float)lid, phi = 0.f;
      #pragma unroll
      for (int k = 0; k < NK; ++k) {
        float d = skap[k] - u;
        phi += smix[k] * __expf(-smix[10 + k] * d * d);
      }
      sphi[lid] = phi * smask[lid];
    }
    __syncthreads();
    if (lid < VV) {
      float acc = 0.f;
      for (int u2 = 0; u2 < UU; ++u2)
        acc += (stext[u2] == lid) ? sphi[u2] : 0.f;
      swv[lid] = (_Float16)acc;
    }
    __syncthreads();

    // ---- L2 input: [x(3), h1(400), w(77), h2(400)] ----
    if (lid < 880)
      svh[lid] = (lid < 3) ? (_Float16)xt[lid]
               : (lid < 403) ? shh[0][lid - 3]
               : (lid < 480) ? swv[lid - 403] : shh[1][lid - 480];
    __syncthreads();
    gatesH<NG23>(WL2, A.b2, svh, sgate, lid);
    __syncthreads();
    if (lid < HH) {
      float ig = sigm(sgate[lid]),        fg = sigm(sgate[400 + lid]);
      float gg = tanhf(sgate[800 + lid]), og = sigm(sgate[1200 + lid]);
      float cn = fg * sc[1][lid] + ig * gg;
      sc[1][lid] = cn; shh[1][lid] = (_Float16)(og * tanhf(cn));
    }
    __syncthreads();

    // ---- L3 input: [x(3), h2(400), w(77), h3(400)] ----
    if (lid < 880)
      svh[lid] = (lid < 3) ? (_Float16)xt[lid]
               : (lid < 403) ? shh[1][lid - 3]
               : (lid < 480) ? swv[lid - 403] : shh[2][lid - 480];
    __syncthreads();
    gatesH<NG23>(WL3, A.b3, svh, sgate, lid);
    __syncthreads();
    if (lid < HH) {
      float ig = sigm(sgate[lid]),        fg = sigm(sgate[400 + lid]);
      float gg = tanhf(sgate[800 + lid]), og = sigm(sgate[1200 + lid]);
      float cn = fg * sc[2][lid] + ig * gg;
      sc[2][lid] = cn; shh[2][lid] = (_Float16)(og * tanhf(cn));
    }
    __syncthreads();

    // ---- out-proj: input [h1|h2|h3] (1200 halfs) ----
    svh[lid] = (lid < 400) ? shh[0][lid]
             : (lid < 800) ? shh[1][lid - 400] : shh[2][lid - 800];
    if (lid < 176) svh[1024 + lid] = shh[2][224 + lid];
    __syncthreads();
    {
      int o = lid & 127, kpart = lid >> 7;
      const unsigned int* wo = WO + o;
      const h2* vh = (const h2*)svh;
      float a = 0.f;
      #pragma unroll 5
      for (int kp = kpart * 75; kp < kpart * 75 + 75; ++kp)
        a = FDOT2(toh2(wo[kp * 128]), vh[kp], a);
      pO2[kpart][o] = a;
    }
    __syncthreads();
    if (lid < NO) {
      float r = A.bout[lid];
      #pragma unroll
      for (int q = 0; q < 8; ++q) r += pO2[q][lid];
      A.out[((size_t)b * TT + t) * NO + lid] = r;
    }
    __syncthreads();
  }
}

extern "C" void kernel_launch(void* const* d_in, const int* in_sizes, int n_in,
                              void* d_out, int out_size, void* d_ws, size_t ws_size,
                              hipStream_t stream) {
  Args a;
  a.x    = (const float*)d_in[0];
  a.text = (const int*)  d_in[1];
  a.mask = (const float*)d_in[2];
  a.Wih1 = (const float*)d_in[3];  a.Whh1 = (const float*)d_in[4];  a.b1 = (const float*)d_in[5];
  a.Wih2 = (const float*)d_in[6];  a.Whh2 = (const float*)d_in[7];  a.b2 = (const float*)d_in[8];
  a.Wih3 = (const float*)d_in[9];  a.Whh3 = (const float*)d_in[10]; a.b3 = (const float*)d_in[11];
  a.Wwin = (const float*)d_in[12]; a.bwin = (const float*)d_in[13];
  a.Wout = (const float*)d_in[14]; a.bout = (const float*)d_in[15];
  a.out  = (float*)d_out;
  a.ws   = (float*)d_ws;
  void* kargs[] = { &a };
  hipLaunchCooperativeKernel((const void*)hsnet_kernel, dim3(NWG), dim3(NTH),
                             kargs, 0, stream);
}

// Round 10
// 41519.791 us; speedup vs baseline: 3.7116x; 1.1517x over previous
//
// Round 10: sync-diet + MLP on r9's passing structure.
// r9 PMC: VALU halved but time -1.57x -> ~40us/step of sync-skew + latency.
// Changes: (1) syncs ~20 -> ~7/step: staging merged into cell phases;
// attention entirely in wave-0 registers+shuffles (kappa/alpha/beta in VGPRs,
// w via shfl scan; 2 syncs); out-proj batched x4 steps from LDS h-ring with
// write folded into next L1 phase. (2) gate matvec unroll 4 (~2x outstanding
// loads). Weights layout identical to r9 + new f16 Wwin region.

#include <hip/hip_runtime.h>
#include <hip/hip_cooperative_groups.h>

namespace cg = cooperative_groups;

#define HH 400
#define NK 10
#define VV 77
#define NO 121
#define TT 600
#define UU 64

#define NWG 64
#define NTH 1024

#define NG1  60     // L1: K=480 (x3,w77,h1 400)
#define NG23 110    // L2/L3: K=880
#define KPO  600    // out: K=1200 half2 pairs

// u32 offsets in ws (layout identical to r9, + Wwin f16 region)
#define O_L1  0
#define O_L2  384000
#define O_L3  1088000
#define O_OUT 1792000
#define O_WW  1868800              // Wwin f16: 60 lanes x 100 u32
#define N_TOT 1874800              // 7.50 MB

typedef _Float16 h2 __attribute__((ext_vector_type(2)));

struct Args {
  const float* __restrict__ x;
  const int*   __restrict__ text;
  const float* __restrict__ mask;
  const float* __restrict__ Wih1; const float* __restrict__ Whh1; const float* __restrict__ b1;
  const float* __restrict__ Wih2; const float* __restrict__ Whh2; const float* __restrict__ b2;
  const float* __restrict__ Wih3; const float* __restrict__ Whh3; const float* __restrict__ b3;
  const float* __restrict__ Wwin; const float* __restrict__ bwin;
  const float* __restrict__ Wout; const float* __restrict__ bout;
  float* __restrict__ out;
  float* __restrict__ ws;
};

__device__ __forceinline__ float sigm(float v) { return 1.0f / (1.0f + __expf(-v)); }

#if defined(__has_builtin)
#if __has_builtin(__builtin_amdgcn_fdot2)
#define FDOT2(a,b,c) __builtin_amdgcn_fdot2((a),(b),(c),false)
#endif
#endif
#ifndef FDOT2
#define FDOT2(a,b,c) fmaf((float)(a).x,(float)(b).x, fmaf((float)(a).y,(float)(b).y,(c)))
#endif

__device__ __forceinline__ h2 toh2(unsigned int u) { return __builtin_bit_cast(h2, u); }

__device__ __forceinline__ float dot4(uint4 p, uint4 v, float a) {
  a = FDOT2(toh2(p.x), toh2(v.x), a);
  a = FDOT2(toh2(p.y), toh2(v.y), a);
  a = FDOT2(toh2(p.z), toh2(v.z), a);
  a = FDOT2(toh2(p.w), toh2(v.w), a);
  return a;
}

__device__ __forceinline__ unsigned int packh2(float f0, float f1) {
  unsigned short lo = __builtin_bit_cast(unsigned short, (_Float16)f0);
  unsigned short hi = __builtin_bit_cast(unsigned short, (_Float16)f1);
  return (unsigned int)lo | ((unsigned int)hi << 16);
}

// Gate matvec: 1600 rows x K=8*NG. Threads 0..575 own rows {lid,1024+lid};
// 576..1023 own row lid. Weights W4[g*1600 + r] (uint4 = 8 halfs of k).
template<int NG>
__device__ __forceinline__ void gatesH(const unsigned int* __restrict__ Wu,
    const float* __restrict__ bias, const _Float16* __restrict__ svh,
    float* __restrict__ sgate, int lid)
{
  const uint4* W4 = (const uint4*)Wu;
  const uint4* vp = (const uint4*)svh;
  if (lid < 576) {
    float a0 = bias[lid], a1 = bias[1024 + lid];
    const uint4* p0 = W4 + lid;
    const uint4* p1 = W4 + 1024 + lid;
    #pragma unroll 4
    for (int g = 0; g < NG; ++g) {
      uint4 vv = vp[g];
      a0 = dot4(p0[g * 1600], vv, a0);
      a1 = dot4(p1[g * 1600], vv, a1);
    }
    sgate[lid] = a0; sgate[1024 + lid] = a1;
  } else {
    float a0 = bias[lid];
    const uint4* p0 = W4 + lid;
    #pragma unroll 4
    for (int g = 0; g < NG; ++g)
      a0 = dot4(p0[g * 1600], vp[g], a0);
    sgate[lid] = a0;
  }
}

__global__ __launch_bounds__(1024) void hsnet_kernel(Args A) {
  cg::grid_group grid = cg::this_grid();
  const int lid  = threadIdx.x;
  const int b    = blockIdx.x;
  const int lane = lid & 63;
  const int wv   = lid >> 6;
  unsigned int* __restrict__ wsu = (unsigned int*)A.ws;

  // ============ prologue: one-time weight conversion to f16 ============
  for (int i = b * NTH + lid; i < N_TOT; i += NWG * NTH) {
    float f0, f1;
    if (i < O_L2) {
      int u = i, g = u / 6400, rem = u - g * 6400, r = rem >> 2, jj = rem & 3;
      int k0 = 8 * g + 2 * jj;
      if (k0 < 80) { f0 = A.Wih1[r * 80 + k0];       f1 = A.Wih1[r * 80 + k0 + 1]; }
      else         { f0 = A.Whh1[r * 400 + k0 - 80]; f1 = A.Whh1[r * 400 + k0 - 79]; }
    } else if (i < O_L3) {
      int u = i - O_L2, g = u / 6400, rem = u - g * 6400, r = rem >> 2, jj = rem & 3;
      int k0 = 8 * g + 2 * jj;
      if (k0 < 480) { f0 = A.Wih2[r * 480 + k0];        f1 = A.Wih2[r * 480 + k0 + 1]; }
      else          { f0 = A.Whh2[r * 400 + k0 - 480];  f1 = A.Whh2[r * 400 + k0 - 479]; }
    } else if (i < O_OUT) {
      int u = i - O_L3, g = u / 6400, rem = u - g * 6400, r = rem >> 2, jj = rem & 3;
      int k0 = 8 * g + 2 * jj;
      if (k0 < 480) { f0 = A.Wih3[r * 480 + k0];        f1 = A.Wih3[r * 480 + k0 + 1]; }
      else          { f0 = A.Whh3[r * 400 + k0 - 480];  f1 = A.Whh3[r * 400 + k0 - 479]; }
    } else if (i < O_WW) {
      int u = i - O_OUT, kp = u >> 7, o = u & 127, k0 = 2 * kp;
      f0 = (o < NO) ? A.Wout[o * 1200 + k0]     : 0.0f;
      f1 = (o < NO) ? A.Wout[o * 1200 + k0 + 1] : 0.0f;
    } else {                                   // Wwin f16: [lane][p], lane=2g+half
      int u = i - O_WW, ln = u / 100, p = u - ln * 100;
      int g = ln >> 1, half = ln & 1, k0 = half * 200 + 2 * p;
      f0 = A.Wwin[g * HH + k0]; f1 = A.Wwin[g * HH + k0 + 1];
    }
    wsu[i] = packh2(f0, f1);
  }
  grid.sync();   // sole cross-WG event

  const unsigned int* __restrict__ WL1  = wsu + O_L1;
  const unsigned int* __restrict__ WL2  = wsu + O_L2;
  const unsigned int* __restrict__ WL3  = wsu + O_L3;
  const unsigned int* __restrict__ WO   = wsu + O_OUT;
  const unsigned int* __restrict__ WWIN = wsu + O_WW;

  // ============ per-WG LDS state ============
  __shared__ alignas(16) _Float16 svh1[480];    // L1 in: [x3, w77, h1 400]
  __shared__ alignas(16) _Float16 svh2[880];    // L2 in: [x3, h1 400, w77, h2 400]
  __shared__ alignas(16) _Float16 svh3[880];    // L3 in: [x3, h2 400, w77, h3 400]
  __shared__ alignas(16) _Float16 sOh[4][1200]; // out-ring: [h1|h2|h3] per t&3
  __shared__ float sgate[1600];
  __shared__ float sc[3][HH];
  __shared__ float pOc[8][128][4];

  // init
  if (lid < 480) svh1[lid] = (_Float16)0.f;
  if (lid < 880) { svh2[lid] = (_Float16)0.f; svh3[lid] = (_Float16)0.f; }
  if (lid < HH) { sc[0][lid] = 0.f; sc[1][lid] = 0.f; sc[2][lid] = 0.f; }
  if (lid < 3) svh1[lid] = (_Float16)A.x[((size_t)b * TT + 0) * 3 + lid];

  // wave-0 attention register state
  float kapr[NK];
  #pragma unroll
  for (int k = 0; k < NK; ++k) kapr[k] = 0.f;
  float maskr = A.mask[b * UU + lane];
  int   textr = A.text[b * UU + lane];
  float bwin_r = (lane < 60 && !(lane & 1)) ? A.bwin[lane >> 1] : 0.f;
  __syncthreads();

  // ============ time loop ============
  for (int t = 0; t < TT; ++t) {
    // -- phase 0 (folded): out write for batch t-4..t-1 --
    if (t >= 4 && (t & 3) == 0 && lid < 512) {
      int c = lid >> 7, o = lid & 127;
      if (o < NO) {
        float r = A.bout[o];
        #pragma unroll
        for (int q = 0; q < 8; ++q) r += pOc[q][o][c];
        A.out[((size_t)b * TT + (t - 4) + c) * NO + o] = r;
      }
    }
    // -- phase 1: L1 gates --
    gatesH<NG1>(WL1, A.b1, svh1, sgate, lid);
    __syncthreads();
    // -- phase 2: L1 cell + staging --
    if (lid < HH) {
      float ig = sigm(sgate[lid]),        fg = sigm(sgate[400 + lid]);
      float gg = tanhf(sgate[800 + lid]), og = sigm(sgate[1200 + lid]);
      float cn = fg * sc[0][lid] + ig * gg;
      sc[0][lid] = cn;
      _Float16 hh = (_Float16)(og * tanhf(cn));
      svh2[3 + lid] = hh; svh1[80 + lid] = hh; sOh[t & 3][lid] = hh;
    }
    if (lid < 3) {
      _Float16 xv = (_Float16)A.x[((size_t)b * TT + t) * 3 + lid];
      svh2[lid] = xv; svh3[lid] = xv;
    }
    __syncthreads();
    // -- phase 3: attention (wave 0, registers + shuffles) --
    if (wv == 0) {
      const h2* hO = (const h2*)sOh[t & 3];          // h1 pairs, aligned
      float m = 0.f;
      if (lane < 60) {
        const uint4* ww = (const uint4*)WWIN + lane * 25;
        const h2* hp = hO + (lane & 1) * 100;
        float acc = 0.f;
        #pragma unroll 5
        for (int p = 0; p < 25; ++p) {
          uint4 wq = ww[p];
          acc = FDOT2(toh2(wq.x), hp[4 * p + 0], acc);
          acc = FDOT2(toh2(wq.y), hp[4 * p + 1], acc);
          acc = FDOT2(toh2(wq.z), hp[4 * p + 2], acc);
          acc = FDOT2(toh2(wq.w), hp[4 * p + 3], acc);
        }
        m = acc;
      }
      m += __shfl_xor(m, 1);
      float mix = 0.f;
      if (lane < 60 && !(lane & 1)) mix = __expf(m + bwin_r);
      float alpha[NK], beta[NK];
      #pragma unroll
      for (int k = 0; k < NK; ++k) {
        alpha[k] = __shfl(mix, 2 * k);
        beta[k]  = __shfl(mix, 20 + 2 * k);
        kapr[k] += __shfl(mix, 40 + 2 * k);
      }
      float u = (float)lane, phi = 0.f;
      #pragma unroll
      for (int k = 0; k < NK; ++k) {
        float d = kapr[k] - u;
        phi += alpha[k] * __expf(-beta[k] * d * d);
      }
      phi *= maskr;
      float w0a = 0.f, w1a = 0.f;
      #pragma unroll 8
      for (int uu = 0; uu < UU; ++uu) {
        int   tu = __shfl(textr, uu);
        float pu = __shfl(phi, uu);
        w0a += (tu == lane)      ? pu : 0.f;
        w1a += (tu == lane + 64) ? pu : 0.f;
      }
      if (lane < VV) {
        _Float16 wh = (_Float16)w0a;
        svh1[3 + lane] = wh; svh2[403 + lane] = wh; svh3[403 + lane] = wh;
      }
      if (lane + 64 < VV) {
        _Float16 wh = (_Float16)w1a;
        svh1[67 + lane] = wh; svh2[467 + lane] = wh; svh3[467 + lane] = wh;
      }
    }
    __syncthreads();
    // -- phase 4: L2 gates --
    gatesH<NG23>(WL2, A.b2, svh2, sgate, lid);
    __syncthreads();
    // -- phase 5: L2 cell + staging --
    if (lid < HH) {
      float ig = sigm(sgate[lid]),        fg = sigm(sgate[400 + lid]);
      float gg = tanhf(sgate[800 + lid]), og = sigm(sgate[1200 + lid]);
      float cn = fg * sc[1][lid] + ig * gg;
      sc[1][lid] = cn;
      _Float16 hh = (_Float16)(og * tanhf(cn));
      svh3[3 + lid] = hh; svh2[480 + lid] = hh; sOh[t & 3][400 + lid] = hh;
    }
    __syncthreads();
    // -- phase 6: L3 gates --
    gatesH<NG23>(WL3, A.b3, svh3, sgate, lid);
    __syncthreads();
    // -- phase 7: L3 cell + staging + x(t+1) --
    if (lid < HH) {
      float ig = sigm(sgate[lid]),        fg = sigm(sgate[400 + lid]);
      float gg = tanhf(sgate[800 + lid]), og = sigm(sgate[1200 + lid]);
      float cn = fg * sc[2][lid] + ig * gg;
      sc[2][lid] = cn;
      _Float16 hh = (_Float16)(og * tanhf(cn));
      svh3[480 + lid] = hh; sOh[t & 3][800 + lid] = hh;
    }
    if (lid < 3 && t + 1 < TT)
      svh1[lid] = (_Float16)A.x[((size_t)b * TT + (t + 1)) * 3 + lid];
    __syncthreads();
    // -- phase 8: batched out-proj every 4 steps --
    if ((t & 3) == 3) {
      int o = lid & 127, kp8 = lid >> 7;
      const unsigned int* wo = WO + o;
      const h2* c0 = (const h2*)sOh[0];
      const h2* c1 = (const h2*)sOh[1];
      const h2* c2 = (const h2*)sOh[2];
      const h2* c3 = (const h2*)sOh[3];
      float a0 = 0.f, a1 = 0.f, a2 = 0.f, a3 = 0.f;
      #pragma unroll 5
      for (int kp = kp8 * 75; kp < kp8 * 75 + 75; ++kp) {
        h2 wq = toh2(wo[kp * 128]);
        a0 = FDOT2(wq, c0[kp], a0);
        a1 = FDOT2(wq, c1[kp], a1);
        a2 = FDOT2(wq, c2[kp], a2);
        a3 = FDOT2(wq, c3[kp], a3);
      }
      pOc[kp8][o][0] = a0; pOc[kp8][o][1] = a1;
      pOc[kp8][o][2] = a2; pOc[kp8][o][3] = a3;
      __syncthreads();
    }
  }
  // final out batch (t0 = 596)
  if (lid < 512) {
    int c = lid >> 7, o = lid & 127;
    if (o < NO) {
      float r = A.bout[o];
      #pragma unroll
      for (int q = 0; q < 8; ++q) r += pOc[q][o][c];
      A.out[((size_t)b * TT + 596 + c) * NO + o] = r;
    }
  }
}

extern "C" void kernel_launch(void* const* d_in, const int* in_sizes, int n_in,
                              void* d_out, int out_size, void* d_ws, size_t ws_size,
                              hipStream_t stream) {
  Args a;
  a.x    = (const float*)d_in[0];
  a.text = (const int*)  d_in[1];
  a.mask = (const float*)d_in[2];
  a.Wih1 = (const float*)d_in[3];  a.Whh1 = (const float*)d_in[4];  a.b1 = (const float*)d_in[5];
  a.Wih2 = (const float*)d_in[6];  a.Whh2 = (const float*)d_in[7];  a.b2 = (const float*)d_in[8];
  a.Wih3 = (const float*)d_in[9];  a.Whh3 = (const float*)d_in[10]; a.b3 = (const float*)d_in[11];
  a.Wwin = (const float*)d_in[12]; a.bwin = (const float*)d_in[13];
  a.Wout = (const float*)d_in[14]; a.bout = (const float*)d_in[15];
  a.out  = (float*)d_out;
  a.ws   = (float*)d_ws;
  void* kargs[] = { &a };
  hipLaunchCooperativeKernel((const void*)hsnet_kernel, dim3(NWG), dim3(NTH),
                             kargs, 0, stream);
}